// Round 4
// baseline (729.539 us; speedup 1.0000x reference)
//
#include <hip/hip_runtime.h>

#define D 128
#define NTILE 32
#define NBLK 128      // blocks for hist/bin passes
#define BSHIFT 6      // 64 nodes per bucket
#define CAP 2560      // max bucket edges staged per LDS chunk (mean 2048, sigma 45)

__device__ __forceinline__ unsigned short f2bf(float f) {
    union { float f; unsigned int u; } c; c.f = f;
    unsigned int b = c.u;
    unsigned int r = (b + 0x7FFFu + ((b >> 16) & 1u)) >> 16;  // RTN-even
    return (unsigned short)r;
}
__device__ __forceinline__ float bf2f(unsigned short s) {
    union { unsigned int u; float f; } c; c.u = ((unsigned int)s) << 16;
    return c.f;
}

// ---------------------------------------------------------------------------
// Kernel 0: W [o][k] -> Wt [k][o]
// ---------------------------------------------------------------------------
__global__ void k_transpose_w(const float* __restrict__ W, float* __restrict__ Wt) {
    int idx = blockIdx.x * blockDim.x + threadIdx.x;
    if (idx < D * D) {
        int o = idx >> 7;
        int k = idx & (D - 1);
        Wt[k * D + o] = W[idx];
    }
}

// ---------------------------------------------------------------------------
// Kernel 1: h = x @ W^T  (fp32 compute, bf16 output)
// ---------------------------------------------------------------------------
__global__ __launch_bounds__(256, 2) void k_gemm(const float* __restrict__ x,
                                                 const float* __restrict__ Wt,
                                                 unsigned short* __restrict__ h) {
    __shared__ float wt[D * D];
    int t = threadIdx.x;

    const float4* Wt4 = (const float4*)Wt;
    float4* wt4 = (float4*)wt;
#pragma unroll
    for (int i = 0; i < (D * D / 4) / 256; i++)
        wt4[t + i * 256] = Wt4[t + i * 256];
    __syncthreads();

    const int n0 = blockIdx.x * NTILE;
    const int to = t & 31;
    const int tn = t >> 5;

    float acc[4][4];
#pragma unroll
    for (int a = 0; a < 4; a++)
#pragma unroll
        for (int b = 0; b < 4; b++) acc[a][b] = 0.0f;

    const float* xb = x + (size_t)(n0 + tn * 4) * D;

    for (int k = 0; k < D; k += 4) {
        float4 xa[4], wb[4];
#pragma unroll
        for (int j = 0; j < 4; j++)
            xa[j] = *(const float4*)(xb + (size_t)j * D + k);
#pragma unroll
        for (int kk = 0; kk < 4; kk++)
            wb[kk] = *(const float4*)&wt[(k + kk) * D + to * 4];
#pragma unroll
        for (int j = 0; j < 4; j++) {
            acc[j][0] += xa[j].x * wb[0].x + xa[j].y * wb[1].x + xa[j].z * wb[2].x + xa[j].w * wb[3].x;
            acc[j][1] += xa[j].x * wb[0].y + xa[j].y * wb[1].y + xa[j].z * wb[2].y + xa[j].w * wb[3].y;
            acc[j][2] += xa[j].x * wb[0].z + xa[j].y * wb[1].z + xa[j].z * wb[2].z + xa[j].w * wb[3].z;
            acc[j][3] += xa[j].x * wb[0].w + xa[j].y * wb[1].w + xa[j].z * wb[2].w + xa[j].w * wb[3].w;
        }
    }

    unsigned short* hb = h + (size_t)(n0 + tn * 4) * D + to * 4;
#pragma unroll
    for (int j = 0; j < 4; j++) {
        ushort4 r;
        r.x = f2bf(acc[j][0]); r.y = f2bf(acc[j][1]);
        r.z = f2bf(acc[j][2]); r.w = f2bf(acc[j][3]);
        *(ushort4*)(hb + (size_t)j * D) = r;
    }
}

// ---------------------------------------------------------------------------
// Kernel 2: per-block bucket histogram (LDS), write counts[bucket][block].
// No global atomics.
// ---------------------------------------------------------------------------
__global__ __launch_bounds__(256) void k_hist(const int* __restrict__ dst,
                                              int* __restrict__ counts,
                                              int E, int nb, int epb) {
    extern __shared__ int hist[];  // nb ints
    const int t = threadIdx.x;
    for (int i = t; i < nb; i += 256) hist[i] = 0;
    __syncthreads();
    const int beg = blockIdx.x * epb;
    const int end = min(beg + epb, E);
    for (int e = beg + t; e < end; e += 256) atomicAdd(&hist[dst[e] >> BSHIFT], 1);
    __syncthreads();
    for (int i = t; i < nb; i += 256) counts[i * NBLK + blockIdx.x] = hist[i];
}

// ---------------------------------------------------------------------------
// Kernel 3: exclusive scan of counts[nb*NBLK] -> offs (bucket-major order).
// ---------------------------------------------------------------------------
__global__ __launch_bounds__(1024) void k_scan(const int* __restrict__ counts,
                                               int* __restrict__ offs, int n) {
    __shared__ int sums[1024];
    const int t = threadIdx.x;
    const int chunk = (n + 1023) / 1024;
    const int start = t * chunk;
    const int end = min(start + chunk, n);

    int s = 0;
    for (int i = start; i < end; i++) s += counts[i];
    sums[t] = s;
    __syncthreads();

    for (int off = 1; off < 1024; off <<= 1) {
        int v = (t >= off) ? sums[t - off] : 0;
        __syncthreads();
        sums[t] += v;
        __syncthreads();
    }

    int base = sums[t] - s;
    for (int i = start; i < end; i++) {
        offs[i] = base;
        base += counts[i];
    }
}

// ---------------------------------------------------------------------------
// Kernel 4: bin edges into buckets. Each block owns an edge range and its
// exclusive slice of every bucket (from offs) -> no global atomics; LDS
// cursors only. packed = src | (dst&63)<<17.
// ---------------------------------------------------------------------------
__global__ __launch_bounds__(256) void k_bin(const int* __restrict__ src,
                                             const int* __restrict__ dst,
                                             const int* __restrict__ offs,
                                             unsigned* __restrict__ packed,
                                             int E, int nb, int epb) {
    extern __shared__ int cur[];  // nb ints
    const int t = threadIdx.x;
    for (int i = t; i < nb; i += 256) cur[i] = offs[i * NBLK + blockIdx.x];
    __syncthreads();
    const int beg = blockIdx.x * epb;
    const int end = min(beg + epb, E);
    for (int e = beg + t; e < end; e += 256) {
        int d = dst[e];
        int s = src[e];
        int bk = d >> BSHIFT;
        int pos = atomicAdd(&cur[bk], 1);
        packed[pos] = (unsigned)s | ((unsigned)(d & 63) << 17);
    }
}

// ---------------------------------------------------------------------------
// Kernel 5: one block per bucket (64 dst nodes). LDS counting-sort of the
// bucket's edges by local dst, then each half-wave accumulates its 8 nodes
// with 4-deep independent h loads. Chunk loop handles >CAP buckets safely.
// ---------------------------------------------------------------------------
__global__ __launch_bounds__(256) void k_gather(const unsigned short* __restrict__ h,
                                                const unsigned* __restrict__ packed,
                                                const int* __restrict__ offs,
                                                float* __restrict__ out,
                                                int N, int nb, int E) {
    __shared__ unsigned lsrc[CAP];
    __shared__ int cnt[64];
    __shared__ int off[65];
    __shared__ int curs[64];

    const int b = blockIdx.x;
    const int t = threadIdx.x;
    const int hw = t >> 5;          // half-wave 0..7
    const int f = (t & 31) << 2;    // feature offset

    const int bbeg = offs[b * NBLK];
    const int bend = (b + 1 < nb) ? offs[(b + 1) * NBLK] : E;

    float4 acc[8];
#pragma unroll
    for (int r = 0; r < 8; r++) acc[r] = make_float4(0.f, 0.f, 0.f, 0.f);

    for (int cbeg = bbeg; cbeg < bend; cbeg += CAP) {
        const int sz = min(CAP, bend - cbeg);

        if (t < 64) cnt[t] = 0;
        __syncthreads();
        for (int i = t; i < sz; i += 256) atomicAdd(&cnt[packed[cbeg + i] >> 17], 1);
        __syncthreads();
        if (t == 0) {
            int s = 0;
#pragma unroll
            for (int j = 0; j < 64; j++) { off[j] = s; s += cnt[j]; }
            off[64] = s;
        }
        __syncthreads();
        if (t < 64) curs[t] = off[t];
        __syncthreads();
        for (int i = t; i < sz; i += 256) {
            unsigned p = packed[cbeg + i];
            int pos = atomicAdd(&curs[p >> 17], 1);
            lsrc[pos] = p & 0x1FFFFu;
        }
        __syncthreads();

#pragma unroll
        for (int r = 0; r < 8; r++) {
            const int nl = hw + (r << 3);
            int j = off[nl];
            const int je = off[nl + 1];
            float4 a = acc[r];
            for (; j + 3 < je; j += 4) {
                int s0 = lsrc[j], s1 = lsrc[j + 1], s2 = lsrc[j + 2], s3 = lsrc[j + 3];
                ushort4 v0 = *(const ushort4*)(h + (size_t)s0 * D + f);
                ushort4 v1 = *(const ushort4*)(h + (size_t)s1 * D + f);
                ushort4 v2 = *(const ushort4*)(h + (size_t)s2 * D + f);
                ushort4 v3 = *(const ushort4*)(h + (size_t)s3 * D + f);
                a.x += bf2f(v0.x) + bf2f(v1.x) + bf2f(v2.x) + bf2f(v3.x);
                a.y += bf2f(v0.y) + bf2f(v1.y) + bf2f(v2.y) + bf2f(v3.y);
                a.z += bf2f(v0.z) + bf2f(v1.z) + bf2f(v2.z) + bf2f(v3.z);
                a.w += bf2f(v0.w) + bf2f(v1.w) + bf2f(v2.w) + bf2f(v3.w);
            }
            for (; j < je; j++) {
                int s0 = lsrc[j];
                ushort4 v0 = *(const ushort4*)(h + (size_t)s0 * D + f);
                a.x += bf2f(v0.x); a.y += bf2f(v0.y);
                a.z += bf2f(v0.z); a.w += bf2f(v0.w);
            }
            acc[r] = a;
        }
        __syncthreads();
    }

#pragma unroll
    for (int r = 0; r < 8; r++) {
        int node = (b << BSHIFT) + hw + (r << 3);
        if (node < N) *(float4*)(out + (size_t)node * D + f) = acc[r];
    }
}

extern "C" void kernel_launch(void* const* d_in, const int* in_sizes, int n_in,
                              void* d_out, int out_size, void* d_ws, size_t ws_size,
                              hipStream_t stream) {
    const float* x = (const float*)d_in[0];   // [N, 128]
    const float* W = (const float*)d_in[1];   // [128, 128]
    const int* ei  = (const int*)d_in[2];     // [2, E] flat
    float* out = (float*)d_out;               // [N, 128]

    const int N = in_sizes[0] / D;            // 100000
    const int E = in_sizes[2] / 2;            // 3200000
    const int nb = (N + 63) >> BSHIFT;        // 1563 buckets
    const int epb = (E + NBLK - 1) / NBLK;    // edges per hist/bin block

    const int* srcp = ei;
    const int* dstp = ei + E;

    // workspace layout (16B-aligned slabs)
    char* ws = (char*)d_ws;
    float* Wt = (float*)ws;          ws += (size_t)D * D * 4;                 // 64 KB
    unsigned short* h = (unsigned short*)ws;
                                     ws += (size_t)N * D * 2;                 // 25.6 MB
    unsigned* packed = (unsigned*)ws; ws += (size_t)E * 4;                    // 12.8 MB
    int* counts = (int*)ws;          ws += (size_t)nb * NBLK * 4;             // 800 KB
    int* offs = (int*)ws;            ws += (size_t)nb * NBLK * 4;             // 800 KB

    k_transpose_w<<<(D * D + 255) / 256, 256, 0, stream>>>(W, Wt);
    k_gemm<<<N / NTILE, 256, 0, stream>>>(x, Wt, h);
    k_hist<<<NBLK, 256, nb * 4, stream>>>(dstp, counts, E, nb, epb);
    k_scan<<<1, 1024, 0, stream>>>(counts, offs, nb * NBLK);
    k_bin<<<NBLK, 256, nb * 4, stream>>>(srcp, dstp, offs, packed, E, nb, epb);
    k_gather<<<nb, 256, 0, stream>>>(h, packed, offs, out, N, nb, E);
}

// Round 5
// 427.365 us; speedup vs baseline: 1.7071x; 1.7071x over previous
//
#include <hip/hip_runtime.h>

#define D 128
#define NTILE 32
#define NBLK 128      // blocks for hist/bin passes
#define BSHIFT 6      // 64 nodes per bucket
#define CAP 2560      // max bucket edges staged per LDS chunk (mean 2048, sigma 45)

__device__ __forceinline__ unsigned short f2bf(float f) {
    union { float f; unsigned int u; } c; c.f = f;
    unsigned int b = c.u;
    unsigned int r = (b + 0x7FFFu + ((b >> 16) & 1u)) >> 16;  // RTN-even
    return (unsigned short)r;
}
__device__ __forceinline__ float bf2f(unsigned short s) {
    union { unsigned int u; float f; } c; c.u = ((unsigned int)s) << 16;
    return c.f;
}

// ---------------------------------------------------------------------------
// Kernel 0: W [o][k] -> Wt [k][o]
// ---------------------------------------------------------------------------
__global__ void k_transpose_w(const float* __restrict__ W, float* __restrict__ Wt) {
    int idx = blockIdx.x * blockDim.x + threadIdx.x;
    if (idx < D * D) {
        int o = idx >> 7;
        int k = idx & (D - 1);
        Wt[k * D + o] = W[idx];
    }
}

// ---------------------------------------------------------------------------
// Kernel 1: h = x @ W^T  (fp32 compute, bf16 output)
// ---------------------------------------------------------------------------
__global__ __launch_bounds__(256, 2) void k_gemm(const float* __restrict__ x,
                                                 const float* __restrict__ Wt,
                                                 unsigned short* __restrict__ h) {
    __shared__ float wt[D * D];
    int t = threadIdx.x;

    const float4* Wt4 = (const float4*)Wt;
    float4* wt4 = (float4*)wt;
#pragma unroll
    for (int i = 0; i < (D * D / 4) / 256; i++)
        wt4[t + i * 256] = Wt4[t + i * 256];
    __syncthreads();

    const int n0 = blockIdx.x * NTILE;
    const int to = t & 31;
    const int tn = t >> 5;

    float acc[4][4];
#pragma unroll
    for (int a = 0; a < 4; a++)
#pragma unroll
        for (int b = 0; b < 4; b++) acc[a][b] = 0.0f;

    const float* xb = x + (size_t)(n0 + tn * 4) * D;

    for (int k = 0; k < D; k += 4) {
        float4 xa[4], wb[4];
#pragma unroll
        for (int j = 0; j < 4; j++)
            xa[j] = *(const float4*)(xb + (size_t)j * D + k);
#pragma unroll
        for (int kk = 0; kk < 4; kk++)
            wb[kk] = *(const float4*)&wt[(k + kk) * D + to * 4];
#pragma unroll
        for (int j = 0; j < 4; j++) {
            acc[j][0] += xa[j].x * wb[0].x + xa[j].y * wb[1].x + xa[j].z * wb[2].x + xa[j].w * wb[3].x;
            acc[j][1] += xa[j].x * wb[0].y + xa[j].y * wb[1].y + xa[j].z * wb[2].y + xa[j].w * wb[3].y;
            acc[j][2] += xa[j].x * wb[0].z + xa[j].y * wb[1].z + xa[j].z * wb[2].z + xa[j].w * wb[3].z;
            acc[j][3] += xa[j].x * wb[0].w + xa[j].y * wb[1].w + xa[j].z * wb[2].w + xa[j].w * wb[3].w;
        }
    }

    unsigned short* hb = h + (size_t)(n0 + tn * 4) * D + to * 4;
#pragma unroll
    for (int j = 0; j < 4; j++) {
        ushort4 r;
        r.x = f2bf(acc[j][0]); r.y = f2bf(acc[j][1]);
        r.z = f2bf(acc[j][2]); r.w = f2bf(acc[j][3]);
        *(ushort4*)(hb + (size_t)j * D) = r;
    }
}

// ---------------------------------------------------------------------------
// Kernel 2: per-block bucket histogram (LDS), write counts[bucket][block].
// ---------------------------------------------------------------------------
__global__ __launch_bounds__(256) void k_hist(const int* __restrict__ dst,
                                              int* __restrict__ counts,
                                              int E, int nb, int epb) {
    extern __shared__ int hist[];  // nb ints
    const int t = threadIdx.x;
    for (int i = t; i < nb; i += 256) hist[i] = 0;
    __syncthreads();
    const int beg = blockIdx.x * epb;
    const int end = min(beg + epb, E);
    for (int e = beg + t; e < end; e += 256) atomicAdd(&hist[dst[e] >> BSHIFT], 1);
    __syncthreads();
    for (int i = t; i < nb; i += 256) counts[i * NBLK + blockIdx.x] = hist[i];
}

// ---------------------------------------------------------------------------
// Kernel 3a: per-bucket scan. Block b: exclusive prefix of its 128
// block-counts (LDS Hillis-Steele) -> woffs, bucket total -> btot[b].
// Fully parallel across 1563 buckets.
// ---------------------------------------------------------------------------
__global__ __launch_bounds__(128) void k_scan_bucket(const int* __restrict__ counts,
                                                     int* __restrict__ woffs,
                                                     int* __restrict__ btot, int nb) {
    __shared__ int s[NBLK];
    const int b = blockIdx.x;
    const int t = threadIdx.x;
    int c = counts[b * NBLK + t];
    s[t] = c;
    __syncthreads();
#pragma unroll
    for (int off = 1; off < NBLK; off <<= 1) {
        int v = (t >= off) ? s[t - off] : 0;
        __syncthreads();
        s[t] += v;
        __syncthreads();
    }
    woffs[b * NBLK + t] = s[t] - c;
    if (t == NBLK - 1) btot[b] = s[NBLK - 1];
}

// ---------------------------------------------------------------------------
// Kernel 3b: exclusive scan of btot[nb] -> bbase[nb+1]  (tiny: nb=1563)
// ---------------------------------------------------------------------------
__global__ __launch_bounds__(1024) void k_scan_tot(const int* __restrict__ btot,
                                                   int* __restrict__ bbase, int nb) {
    __shared__ int sums[1024];
    const int t = threadIdx.x;
    const int chunk = (nb + 1023) / 1024;
    const int start = t * chunk;
    const int end = min(start + chunk, nb);

    int s = 0;
    for (int i = start; i < end; i++) s += btot[i];
    sums[t] = s;
    __syncthreads();

    for (int off = 1; off < 1024; off <<= 1) {
        int v = (t >= off) ? sums[t - off] : 0;
        __syncthreads();
        sums[t] += v;
        __syncthreads();
    }

    int base = sums[t] - s;
    for (int i = start; i < end; i++) {
        bbase[i] = base;
        base += btot[i];
    }
    if (t == 1023) bbase[nb] = sums[1023];
}

// ---------------------------------------------------------------------------
// Kernel 4: bin edges into buckets. Block's cursor for bucket i starts at
// bbase[i] + woffs[i][block]. No global atomics; LDS cursors only.
// packed = src | (dst&63)<<17.
// ---------------------------------------------------------------------------
__global__ __launch_bounds__(256) void k_bin(const int* __restrict__ src,
                                             const int* __restrict__ dst,
                                             const int* __restrict__ woffs,
                                             const int* __restrict__ bbase,
                                             unsigned* __restrict__ packed,
                                             int E, int nb, int epb) {
    extern __shared__ int cur[];  // nb ints
    const int t = threadIdx.x;
    for (int i = t; i < nb; i += 256)
        cur[i] = bbase[i] + woffs[i * NBLK + blockIdx.x];
    __syncthreads();
    const int beg = blockIdx.x * epb;
    const int end = min(beg + epb, E);
    for (int e = beg + t; e < end; e += 256) {
        int d = dst[e];
        int s = src[e];
        int bk = d >> BSHIFT;
        int pos = atomicAdd(&cur[bk], 1);
        packed[pos] = (unsigned)s | ((unsigned)(d & 63) << 17);
    }
}

// ---------------------------------------------------------------------------
// Kernel 5: one block per bucket (64 dst nodes). LDS counting-sort by local
// dst, then each half-wave accumulates its 8 nodes with 4-deep independent
// h loads. Bucket range is simply [bbase[b], bbase[b+1]).
// ---------------------------------------------------------------------------
__global__ __launch_bounds__(256) void k_gather(const unsigned short* __restrict__ h,
                                                const unsigned* __restrict__ packed,
                                                const int* __restrict__ bbase,
                                                float* __restrict__ out, int N) {
    __shared__ unsigned lsrc[CAP];
    __shared__ int cnt[64];
    __shared__ int off[65];
    __shared__ int curs[64];

    const int b = blockIdx.x;
    const int t = threadIdx.x;
    const int hw = t >> 5;          // half-wave 0..7
    const int f = (t & 31) << 2;    // feature offset

    const int bbeg = bbase[b];
    const int bend = bbase[b + 1];

    float4 acc[8];
#pragma unroll
    for (int r = 0; r < 8; r++) acc[r] = make_float4(0.f, 0.f, 0.f, 0.f);

    for (int cbeg = bbeg; cbeg < bend; cbeg += CAP) {
        const int sz = min(CAP, bend - cbeg);

        if (t < 64) cnt[t] = 0;
        __syncthreads();
        for (int i = t; i < sz; i += 256) atomicAdd(&cnt[packed[cbeg + i] >> 17], 1);
        __syncthreads();
        if (t == 0) {
            int s = 0;
#pragma unroll
            for (int j = 0; j < 64; j++) { off[j] = s; s += cnt[j]; }
            off[64] = s;
        }
        __syncthreads();
        if (t < 64) curs[t] = off[t];
        __syncthreads();
        for (int i = t; i < sz; i += 256) {
            unsigned p = packed[cbeg + i];
            int pos = atomicAdd(&curs[p >> 17], 1);
            lsrc[pos] = p & 0x1FFFFu;
        }
        __syncthreads();

#pragma unroll
        for (int r = 0; r < 8; r++) {
            const int nl = hw + (r << 3);
            int j = off[nl];
            const int je = off[nl + 1];
            float4 a = acc[r];
            for (; j + 3 < je; j += 4) {
                int s0 = lsrc[j], s1 = lsrc[j + 1], s2 = lsrc[j + 2], s3 = lsrc[j + 3];
                ushort4 v0 = *(const ushort4*)(h + (size_t)s0 * D + f);
                ushort4 v1 = *(const ushort4*)(h + (size_t)s1 * D + f);
                ushort4 v2 = *(const ushort4*)(h + (size_t)s2 * D + f);
                ushort4 v3 = *(const ushort4*)(h + (size_t)s3 * D + f);
                a.x += bf2f(v0.x) + bf2f(v1.x) + bf2f(v2.x) + bf2f(v3.x);
                a.y += bf2f(v0.y) + bf2f(v1.y) + bf2f(v2.y) + bf2f(v3.y);
                a.z += bf2f(v0.z) + bf2f(v1.z) + bf2f(v2.z) + bf2f(v3.z);
                a.w += bf2f(v0.w) + bf2f(v1.w) + bf2f(v2.w) + bf2f(v3.w);
            }
            for (; j < je; j++) {
                int s0 = lsrc[j];
                ushort4 v0 = *(const ushort4*)(h + (size_t)s0 * D + f);
                a.x += bf2f(v0.x); a.y += bf2f(v0.y);
                a.z += bf2f(v0.z); a.w += bf2f(v0.w);
            }
            acc[r] = a;
        }
        __syncthreads();
    }

#pragma unroll
    for (int r = 0; r < 8; r++) {
        int node = (b << BSHIFT) + hw + (r << 3);
        if (node < N) *(float4*)(out + (size_t)node * D + f) = acc[r];
    }
}

extern "C" void kernel_launch(void* const* d_in, const int* in_sizes, int n_in,
                              void* d_out, int out_size, void* d_ws, size_t ws_size,
                              hipStream_t stream) {
    const float* x = (const float*)d_in[0];   // [N, 128]
    const float* W = (const float*)d_in[1];   // [128, 128]
    const int* ei  = (const int*)d_in[2];     // [2, E] flat
    float* out = (float*)d_out;               // [N, 128]

    const int N = in_sizes[0] / D;            // 100000
    const int E = in_sizes[2] / 2;            // 3200000
    const int nb = (N + 63) >> BSHIFT;        // 1563 buckets
    const int epb = (E + NBLK - 1) / NBLK;    // edges per hist/bin block

    const int* srcp = ei;
    const int* dstp = ei + E;

    // workspace layout (16B-aligned slabs)
    char* ws = (char*)d_ws;
    float* Wt = (float*)ws;           ws += (size_t)D * D * 4;                // 64 KB
    unsigned short* h = (unsigned short*)ws;
                                      ws += (size_t)N * D * 2;                // 25.6 MB
    unsigned* packed = (unsigned*)ws; ws += (size_t)E * 4;                    // 12.8 MB
    int* counts = (int*)ws;           ws += (size_t)nb * NBLK * 4;            // 800 KB
    int* woffs = (int*)ws;            ws += (size_t)nb * NBLK * 4;            // 800 KB
    int* btot = (int*)ws;             ws += ((size_t)nb * 4 + 15) & ~15ull;
    int* bbase = (int*)ws;            ws += ((size_t)(nb + 1) * 4 + 15) & ~15ull;

    k_transpose_w<<<(D * D + 255) / 256, 256, 0, stream>>>(W, Wt);
    k_gemm<<<N / NTILE, 256, 0, stream>>>(x, Wt, h);
    k_hist<<<NBLK, 256, nb * 4, stream>>>(dstp, counts, E, nb, epb);
    k_scan_bucket<<<nb, NBLK, 0, stream>>>(counts, woffs, btot, nb);
    k_scan_tot<<<1, 1024, 0, stream>>>(btot, bbase, nb);
    k_bin<<<NBLK, 256, nb * 4, stream>>>(srcp, dstp, woffs, bbase, packed, E, nb, epb);
    k_gather<<<nb, 256, 0, stream>>>(h, packed, bbase, out, N);
}